// Round 2
// baseline (1158.206 us; speedup 1.0000x reference)
//
#include <hip/hip_runtime.h>
#include <math.h>

#define NROWS 65536
#define PER 64
#define BIMG 1024
#define NCLS 36
#define OBJ_DIM 192
#define EMB 200
#define POSD 128
#define HID 1024
#define EPSV 1e-5f

#define KTOT 360     // 192 feat + 35 dist + 128 pos, padded 355 -> 360

// ---------------- k1: fused weight W1f(360,1024) ----------------
// rows 0..191   = dec1_W[0:192]
// rows 192..226 = obj_embed_W(35,200) @ dec1_W[192:392]
// rows 227..354 = dec1_W[392:520]
// rows 355..359 = 0
__global__ __launch_bounds__(256) void k1_w1f(
    const float* __restrict__ obj_embed_W, const float* __restrict__ dec1_W,
    float* __restrict__ W1f)
{
    int idx = blockIdx.x * 256 + threadIdx.x;
    if (idx >= KTOT * HID) return;
    int r = idx / HID, c = idx % HID;
    float v;
    if (r < 192) {
        v = dec1_W[(size_t)r * HID + c];
    } else if (r < 227) {
        int e = r - 192;
        float acc = 0.f;
        for (int j = 0; j < EMB; ++j)
            acc = fmaf(obj_embed_W[e * EMB + j], dec1_W[(size_t)(192 + j) * HID + c], acc);
        v = acc;
    } else if (r < 355) {
        v = dec1_W[(size_t)(r - 227 + 392) * HID + c];
    } else {
        v = 0.f;
    }
    W1f[idx] = v;
}

// A-operand synthesis: X[row][k] without materializing X
__device__ __forceinline__ float load_x(
    const float* __restrict__ features, const float* __restrict__ distribution,
    const float* __restrict__ pos_W, const float* __restrict__ pos_b,
    const float* __restrict__ hS, int row, int rloc, int k)
{
    if (k < 192) return features[(size_t)row * OBJ_DIM + k];
    if (k < 227) return distribution[(size_t)row * (NCLS - 1) + (k - 192)];
    if (k < 355) {
        int j = k - 227;
        float p = pos_b[j];
        p = fmaf(hS[rloc * 4 + 0], pos_W[0 * POSD + j], p);
        p = fmaf(hS[rloc * 4 + 1], pos_W[1 * POSD + j], p);
        p = fmaf(hS[rloc * 4 + 2], pos_W[2 * POSD + j], p);
        p = fmaf(hS[rloc * 4 + 3], pos_W[3 * POSD + j], p);
        return fmaxf(p, 0.0f);
    }
    return 0.0f;
}

// ---------------- fused: (X @ W1f -> bn -> relu -> @ dec2_W) + softmax head ----------------
// one block = 64 rows, 256 threads. Loops 8 col-chunks of 128; Gc never leaves LDS.
__global__ __launch_bounds__(256) void k_fused(
    const float* __restrict__ distribution, const float* __restrict__ features,
    const float* __restrict__ boxes,
    const float* __restrict__ bn4_g, const float* __restrict__ bn4_b,
    const float* __restrict__ bn4_m, const float* __restrict__ bn4_v,
    const float* __restrict__ pos_W, const float* __restrict__ pos_b,
    const float* __restrict__ W1f, const float* __restrict__ dec1_b,
    const float* __restrict__ bn1k_g, const float* __restrict__ bn1k_b,
    const float* __restrict__ bn1k_m, const float* __restrict__ bn1k_v,
    const float* __restrict__ dec2_W, const float* __restrict__ dec2_b,
    float* __restrict__ out)
{
    __shared__ float smem[14848];   // 59392 B
    float* sA  = smem;              // [8][64]    512
    float* sB  = smem + 512;        // [8][128]  1024
    float* hS  = smem + 1536;       // [64][4]    256
    float* Gc  = smem + 1792;       // [64][132] 8448
    float* W2s = smem + 10240;      // [128*36]  4608

    int t = threadIdx.x;
    int row0 = blockIdx.x * 64;

    // per-row bn4'd box features h[0..3]
    if (t < 64) {
        const float* bx = boxes + (size_t)(row0 + t) * 5;
        float x1 = bx[1], y1 = bx[2], x2 = bx[3], y2 = bx[4];
        float w  = x2 - x1 + 1.0f;
        float hh = y2 - y1 + 1.0f;
        float c0 = x1 + 0.5f * w, c1 = y1 + 0.5f * hh;
        hS[t * 4 + 0] = (c0 - bn4_m[0]) * rsqrtf(bn4_v[0] + EPSV) * bn4_g[0] + bn4_b[0];
        hS[t * 4 + 1] = (c1 - bn4_m[1]) * rsqrtf(bn4_v[1] + EPSV) * bn4_g[1] + bn4_b[1];
        hS[t * 4 + 2] = (w  - bn4_m[2]) * rsqrtf(bn4_v[2] + EPSV) * bn4_g[2] + bn4_b[2];
        hS[t * 4 + 3] = (hh - bn4_m[3]) * rsqrtf(bn4_v[3] + EPSV) * bn4_g[3] + bn4_b[3];
    }
    __syncthreads();

    int tx = t & 15, ty = t >> 4;
    int m0 = ty * 4, n0 = tx * 8;       // this thread's 4x8 patch of the 64x128 tile
    int am = t >> 2, ak = (t & 3) * 2;  // staging: A
    int bk = t >> 5, bn = (t & 31) * 4; // staging: B
    int rL = t >> 2, cg = t & 3;        // logits: row, class-group (9 classes)

    float accL[9];
#pragma unroll
    for (int j = 0; j < 9; j++) accL[j] = dec2_b[cg * 9 + j];

    for (int c = 0; c < 8; ++c) {
        int col0 = c * 128;
        float acc[4][8];
#pragma unroll
        for (int i = 0; i < 4; i++)
#pragma unroll
            for (int j = 0; j < 8; j++) acc[i][j] = 0.f;

        for (int k0 = 0; k0 < KTOT; k0 += 8) {
            float a0 = load_x(features, distribution, pos_W, pos_b, hS,
                              row0 + am, am, k0 + ak);
            float a1 = load_x(features, distribution, pos_W, pos_b, hS,
                              row0 + am, am, k0 + ak + 1);
            float4 bv = *(const float4*)(W1f + (size_t)(k0 + bk) * HID + col0 + bn);
            __syncthreads();
            sA[ak * 64 + am] = a0;
            sA[(ak + 1) * 64 + am] = a1;
            *(float4*)&sB[bk * 128 + bn] = bv;
            __syncthreads();
#pragma unroll
            for (int kk = 0; kk < 8; kk++) {
                float4 a  = *(float4*)&sA[kk * 64 + m0];
                float4 b0 = *(float4*)&sB[kk * 128 + n0];
                float4 b1 = *(float4*)&sB[kk * 128 + n0 + 4];
                float av[4] = {a.x, a.y, a.z, a.w};
                float bw[8] = {b0.x, b0.y, b0.z, b0.w, b1.x, b1.y, b1.z, b1.w};
#pragma unroll
                for (int i = 0; i < 4; i++)
#pragma unroll
                    for (int j = 0; j < 8; j++)
                        acc[i][j] = fmaf(av[i], bw[j], acc[i][j]);
            }
        }

        // epilogue: bias + bn1k + relu -> Gc (LDS)
        float scale[8], base[8];
#pragma unroll
        for (int j = 0; j < 8; j++) {
            int cc = col0 + n0 + j;
            float sc = rsqrtf(bn1k_v[cc] + EPSV) * bn1k_g[cc];
            scale[j] = sc;
            base[j]  = (dec1_b[cc] - bn1k_m[cc]) * sc + bn1k_b[cc];
        }
#pragma unroll
        for (int i = 0; i < 4; i++) {
            float v[8];
#pragma unroll
            for (int j = 0; j < 8; j++)
                v[j] = fmaxf(fmaf(acc[i][j], scale[j], base[j]), 0.0f);
            float4 o0 = {v[0], v[1], v[2], v[3]};
            float4 o1 = {v[4], v[5], v[6], v[7]};
            *(float4*)&Gc[(m0 + i) * 132 + n0]     = o0;
            *(float4*)&Gc[(m0 + i) * 132 + n0 + 4] = o1;
        }
        // stage this chunk of dec2_W: rows col0..col0+127, 36 cols (contiguous 4608 floats)
#pragma unroll
        for (int i = 0; i < 18; i++) {
            int e = t + i * 256;
            W2s[e] = dec2_W[(size_t)col0 * NCLS + e];
        }
        __syncthreads();
        // logits accumulation: L[r][:] += Gc[r][k] * W2s[k][:]
        for (int k = 0; k < 128; k++) {
            float gv = Gc[rL * 132 + k];
#pragma unroll
            for (int j = 0; j < 9; j++)
                accL[j] = fmaf(gv, W2s[k * NCLS + cg * 9 + j], accL[j]);
        }
        __syncthreads();
    }

    // stash logits (alias Gc region), then per-row softmax head
    float* L = Gc;
#pragma unroll
    for (int j = 0; j < 9; j++) L[rL * 37 + cg * 9 + j] = accL[j];
    __syncthreads();

    if (t < 64) {
        int row = row0 + t;
        const float* lr = &L[t * 37];
        float m = lr[1];
#pragma unroll
        for (int c = 2; c < 36; c++) m = fmaxf(m, lr[c]);
        float d[35];
        float s = 0.f;
#pragma unroll
        for (int c = 1; c < 36; c++) { float e = expf(lr[c] - m); d[c - 1] = e; s += e; }
        float inv = 1.0f / s;
        float* dout = out + (size_t)row * 35;
#pragma unroll
        for (int j = 0; j < 35; j++) dout[j] = d[j] * inv;
        // pred over dist cols 1..34 (first-occurrence argmax), label = distcol + 1
        float best = -1.f; int bi = 1;
#pragma unroll
        for (int c = 1; c < 35; c++) {
            float v = d[c] * inv;
            if (v > best) { best = v; bi = c; }
        }
        out[(size_t)NROWS * 35 + row] = best;
        out[(size_t)NROWS * 36 + row] = (float)(bi + 1);
    }
}

// ---------------- k4: per-image human argmax over dist[:,0], overwrite ----------------
__global__ __launch_bounds__(64) void k4_human(float* __restrict__ out)
{
    int b = blockIdx.x;
    int t = threadIdx.x;
    int row = b * PER + t;
    float v = out[(size_t)row * 35 + 0];
    int idx = t;
#pragma unroll
    for (int off = 32; off > 0; off >>= 1) {
        float ov = __shfl_down(v, off);
        int   oi = __shfl_down(idx, off);
        if (ov > v || (ov == v && oi < idx)) { v = ov; idx = oi; }
    }
    if (t == 0) {
        int human = b * PER + idx;
        out[(size_t)NROWS * 37 + b] = (float)human;    // human_idx
        out[(size_t)NROWS * 35 + human] = v;           // pred_scores[human] = dist[human,0]
        out[(size_t)NROWS * 36 + human] = 1.0f;        // pred_labels[human] = 1
    }
}

extern "C" void kernel_launch(void* const* d_in, const int* in_sizes, int n_in,
                              void* d_out, int out_size, void* d_ws, size_t ws_size,
                              hipStream_t stream)
{
    (void)in_sizes; (void)n_in; (void)out_size; (void)ws_size;
    const float* distribution = (const float*)d_in[0];
    const float* features     = (const float*)d_in[1];
    const float* boxes        = (const float*)d_in[2];
    const float* obj_embed_W  = (const float*)d_in[3];
    const float* bn4_g        = (const float*)d_in[4];
    const float* bn4_b        = (const float*)d_in[5];
    const float* bn4_m        = (const float*)d_in[6];
    const float* bn4_v        = (const float*)d_in[7];
    const float* pos_W        = (const float*)d_in[8];
    const float* pos_b        = (const float*)d_in[9];
    const float* dec1_W       = (const float*)d_in[10];
    const float* dec1_b       = (const float*)d_in[11];
    const float* bn1k_g       = (const float*)d_in[12];
    const float* bn1k_b       = (const float*)d_in[13];
    const float* bn1k_m       = (const float*)d_in[14];
    const float* bn1k_v       = (const float*)d_in[15];
    const float* dec2_W       = (const float*)d_in[16];
    const float* dec2_b       = (const float*)d_in[17];

    float* out = (float*)d_out;
    float* W1f = (float*)d_ws;   // 360*1024 floats = 1.47 MB only

    k1_w1f<<<(KTOT * HID + 255) / 256, 256, 0, stream>>>(obj_embed_W, dec1_W, W1f);
    k_fused<<<NROWS / 64, 256, 0, stream>>>(distribution, features, boxes,
                                            bn4_g, bn4_b, bn4_m, bn4_v, pos_W, pos_b,
                                            W1f, dec1_b, bn1k_g, bn1k_b, bn1k_m, bn1k_v,
                                            dec2_W, dec2_b, out);
    k4_human<<<BIMG, 64, 0, stream>>>(out);
}

// Round 3
// 629.032 us; speedup vs baseline: 1.8413x; 1.8413x over previous
//
#include <hip/hip_runtime.h>
#include <math.h>

#define NROWS 65536
#define PER 64
#define BIMG 1024
#define NCLS 36
#define OBJ_DIM 192
#define EMB 200
#define POSD 128
#define HID 1024
#define EPSV 1e-5f

#define KP 384            // padded K for GEMM1 (355 real -> 384)
#define XSTR 392          // Xs LDS row stride in bf16 units (uniform bank spread, 16B aligned)
#define GCSTR 72          // Gc row stride in bf16 units (64 + 8)
#define W2KP 1024         // W2T k stride

typedef __attribute__((ext_vector_type(8))) short bf16x8;
typedef __attribute__((ext_vector_type(4))) float f32x4;
typedef __attribute__((ext_vector_type(4))) unsigned short us4;
typedef __attribute__((ext_vector_type(8))) unsigned short us8;

__device__ __forceinline__ unsigned short f2bf(float f) {
    unsigned u = __float_as_uint(f);
    unsigned r = (u + 0x7FFFu + ((u >> 16) & 1u)) >> 16;   // RNE
    return (unsigned short)r;
}
__device__ __forceinline__ float bf2f(unsigned short u) {
    return __uint_as_float(((unsigned)u) << 16);
}

// ---------------- prep: fused+scaled W1f^T (bf16 hi/lo), W2^T (bf16 hi/lo), bias vector ----
// W1fT[h][k]: k<192 -> dec1_W[k][h]; 192..226 -> (obj_embed_W @ dec1_W[192:392])[k-192][h];
// 227..354 -> dec1_W[k+165][h]; >=355 -> 0.  All scaled by bn1k scale sc[h].
__global__ __launch_bounds__(256) void k_prep(
    const float* __restrict__ obj_embed_W, const float* __restrict__ dec1_W,
    const float* __restrict__ dec1_b,
    const float* __restrict__ bn1k_g, const float* __restrict__ bn1k_b,
    const float* __restrict__ bn1k_m, const float* __restrict__ bn1k_v,
    const float* __restrict__ dec2_W,
    unsigned short* __restrict__ W1fT_h, unsigned short* __restrict__ W1fT_l,
    unsigned short* __restrict__ W2T_h, unsigned short* __restrict__ W2T_l,
    float* __restrict__ bs)
{
    int idx = blockIdx.x * 256 + threadIdx.x;
    if (idx < HID * KP) {
        int h = idx / KP, k = idx % KP;
        float sc = rsqrtf(bn1k_v[h] + EPSV) * bn1k_g[h];
        float v;
        if (k < 192) v = dec1_W[(size_t)k * HID + h];
        else if (k < 227) {
            int e = k - 192; float acc = 0.f;
            for (int j = 0; j < EMB; ++j)
                acc = fmaf(obj_embed_W[e * EMB + j], dec1_W[(size_t)(192 + j) * HID + h], acc);
            v = acc;
        } else if (k < 355) v = dec1_W[(size_t)(k - 227 + 392) * HID + h];
        else v = 0.f;
        v *= sc;
        unsigned short hi = f2bf(v);
        W1fT_h[(size_t)h * KP + k] = hi;
        W1fT_l[(size_t)h * KP + k] = f2bf(v - bf2f(hi));
        if (k == 0) bs[h] = (dec1_b[h] - bn1k_m[h]) * sc + bn1k_b[h];
    } else {
        int j = idx - HID * KP;           // 48 * 1024 region
        if (j < 48 * W2KP) {
            int c = j / W2KP, h2 = j % W2KP;
            float v = (c < NCLS) ? dec2_W[(size_t)h2 * NCLS + c] : 0.f;
            unsigned short hi = f2bf(v);
            W2T_h[j] = hi;
            W2T_l[j] = f2bf(v - bf2f(hi));
        }
    }
}

// ---------------- main fused kernel: 64 rows/block ----------------
// GEMM1 (transposed): D[hidden][row] = W1fT(A, global) x Xs(B, LDS), bf16 3-term split.
// Then per 64-hidden sub-round: bias+relu+split -> Gc (LDS) -> GEMM2 MFMA vs W2T (global).
__global__ __launch_bounds__(256, 1) void k_main(
    const float* __restrict__ distribution, const float* __restrict__ features,
    const float* __restrict__ boxes,
    const float* __restrict__ bn4_g, const float* __restrict__ bn4_b,
    const float* __restrict__ bn4_m, const float* __restrict__ bn4_v,
    const float* __restrict__ pos_W, const float* __restrict__ pos_b,
    const unsigned short* __restrict__ W1fT_h, const unsigned short* __restrict__ W1fT_l,
    const unsigned short* __restrict__ W2T_h, const unsigned short* __restrict__ W2T_l,
    const float* __restrict__ bs, const float* __restrict__ dec2_b,
    float* __restrict__ out)
{
    extern __shared__ char smem[];
    unsigned short* XsH = (unsigned short*)smem;        // 64*392 bf16 = 50176 B
    unsigned short* XsL = XsH + 64 * XSTR;              // 50176 B
    unsigned short* GcH = XsL + 64 * XSTR;              // 64*72*2 = 9216 B
    unsigned short* GcL = GcH + 64 * GCSTR;             // 9216 B
    float* Lst = (float*)(XsL + 64 * XSTR);             // aliases Gc region (64*49*4 = 12544 B)

    int t = threadIdx.x;
    int row0 = blockIdx.x * PER;

    // ---- stage X = [features | distribution | pos] as bf16 hi/lo, K padded to 384 ----
    {
        int r = t >> 2;            // 0..63 local row
        int kq = t & 3;            // k quarter (96 each)
        int grow = row0 + r;
        const float* bx = boxes + (size_t)grow * 5;
        float x1 = bx[1], y1 = bx[2], x2 = bx[3], y2 = bx[4];
        float w = x2 - x1 + 1.f, hh = y2 - y1 + 1.f;
        float cs[4] = {x1 + 0.5f * w, y1 + 0.5f * hh, w, hh};
        float hv[4];
#pragma unroll
        for (int i = 0; i < 4; i++)
            hv[i] = (cs[i] - bn4_m[i]) * rsqrtf(bn4_v[i] + EPSV) * bn4_g[i] + bn4_b[i];
        for (int jb = 0; jb < 12; ++jb) {
            int kb = kq * 96 + jb * 8;
            us8 hi8, lo8;
#pragma unroll
            for (int e = 0; e < 8; ++e) {
                int k = kb + e;
                float v;
                if (k < 192) v = features[(size_t)grow * OBJ_DIM + k];
                else if (k < 227) v = distribution[(size_t)grow * (NCLS - 1) + (k - 192)];
                else if (k < 355) {
                    int j = k - 227;
                    float p = pos_b[j];
                    p = fmaf(hv[0], pos_W[j], p);
                    p = fmaf(hv[1], pos_W[POSD + j], p);
                    p = fmaf(hv[2], pos_W[2 * POSD + j], p);
                    p = fmaf(hv[3], pos_W[3 * POSD + j], p);
                    v = fmaxf(p, 0.f);
                } else v = 0.f;
                unsigned short hi = f2bf(v);
                hi8[e] = hi;
                lo8[e] = f2bf(v - bf2f(hi));
            }
            *(us8*)&XsH[r * XSTR + kb] = hi8;
            *(us8*)&XsL[r * XSTR + kb] = lo8;
        }
    }
    __syncthreads();

    int wv = t >> 6, lane = t & 63, lr = lane & 15, lq = lane >> 4;

    f32x4 Lg[3];                       // logit frags: rows 16wv..+15 x classes 48
#pragma unroll
    for (int n = 0; n < 3; n++) Lg[n] = (f32x4){0.f, 0.f, 0.f, 0.f};

    for (int c0 = 0; c0 < 4; ++c0) {   // hidden chunks of 256
        int H0 = c0 * 256;
        f32x4 C[4][4];
#pragma unroll
        for (int j = 0; j < 4; j++)
#pragma unroll
            for (int n = 0; n < 4; n++) C[j][n] = (f32x4){0.f, 0.f, 0.f, 0.f};

        // ---- GEMM1 K-loop: no barriers (Xs read-only) ----
        for (int ks = 0; ks < 12; ++ks) {
            int k0 = ks * 32 + lq * 8;
            bf16x8 ah[4], al[4], bh[4], bl[4];
#pragma unroll
            for (int j = 0; j < 4; j++) {
                size_t off = (size_t)(H0 + 16 * (wv + 4 * j) + lr) * KP + k0;
                ah[j] = *(const bf16x8*)(W1fT_h + off);
                al[j] = *(const bf16x8*)(W1fT_l + off);
            }
#pragma unroll
            for (int n = 0; n < 4; n++) {
                int rb = (16 * n + lr) * XSTR + k0;
                bh[n] = *(const bf16x8*)&XsH[rb];
                bl[n] = *(const bf16x8*)&XsL[rb];
            }
#pragma unroll
            for (int j = 0; j < 4; j++)
#pragma unroll
                for (int n = 0; n < 4; n++)
                    C[j][n] = __builtin_amdgcn_mfma_f32_16x16x32_bf16(ah[j], bh[n], C[j][n], 0, 0, 0);
#pragma unroll
            for (int j = 0; j < 4; j++)
#pragma unroll
                for (int n = 0; n < 4; n++)
                    C[j][n] = __builtin_amdgcn_mfma_f32_16x16x32_bf16(ah[j], bl[n], C[j][n], 0, 0, 0);
#pragma unroll
            for (int j = 0; j < 4; j++)
#pragma unroll
                for (int n = 0; n < 4; n++)
                    C[j][n] = __builtin_amdgcn_mfma_f32_16x16x32_bf16(al[j], bh[n], C[j][n], 0, 0, 0);
        }

        // ---- transform + GEMM2, 4 sub-rounds of 64 hidden ----
        for (int j = 0; j < 4; ++j) {
            __syncthreads();           // Gc free (previous GEMM2 done)
            int hb = H0 + 16 * (wv + 4 * j) + 4 * lq;
            f32x4 bsv = *(const f32x4*)(bs + hb);
#pragma unroll
            for (int n = 0; n < 4; n++) {
                us4 hi4, lo4;
#pragma unroll
                for (int e = 0; e < 4; ++e) {
                    float g = fmaxf(C[j][n][e] + bsv[e], 0.f);
                    unsigned short h16 = f2bf(g);
                    hi4[e] = h16;
                    lo4[e] = f2bf(g - bf2f(h16));
                }
                int gco = (16 * n + lr) * GCSTR + 16 * wv + 4 * lq;
                *(us4*)&GcH[gco] = hi4;
                *(us4*)&GcL[gco] = lo4;
            }
            __syncthreads();           // Gc filled
#pragma unroll
            for (int ks2 = 0; ks2 < 2; ++ks2) {
                int kl = ks2 * 32 + lq * 8;
                bf16x8 a2h = *(const bf16x8*)&GcH[(16 * wv + lr) * GCSTR + kl];
                bf16x8 a2l = *(const bf16x8*)&GcL[(16 * wv + lr) * GCSTR + kl];
                int hg = H0 + 64 * j + kl;
#pragma unroll
                for (int n = 0; n < 3; n++) {
                    size_t woff = (size_t)(16 * n + lr) * W2KP + hg;
                    bf16x8 b2h = *(const bf16x8*)(W2T_h + woff);
                    bf16x8 b2l = *(const bf16x8*)(W2T_l + woff);
                    Lg[n] = __builtin_amdgcn_mfma_f32_16x16x32_bf16(a2h, b2h, Lg[n], 0, 0, 0);
                    Lg[n] = __builtin_amdgcn_mfma_f32_16x16x32_bf16(a2h, b2l, Lg[n], 0, 0, 0);
                    Lg[n] = __builtin_amdgcn_mfma_f32_16x16x32_bf16(a2l, b2h, Lg[n], 0, 0, 0);
                }
            }
        }
    }

    __syncthreads();                   // Gc region now reused as logit stash
#pragma unroll
    for (int n = 0; n < 3; n++)
#pragma unroll
        for (int e = 0; e < 4; ++e)
            Lst[(16 * wv + 4 * lq + e) * 49 + 16 * n + lr] = Lg[n][e];
    __syncthreads();

    // ---- softmax head (proven R2 code) ----
    if (t < 64) {
        int row = row0 + t;
        float lg[36];
#pragma unroll
        for (int c = 1; c < 36; ++c) lg[c] = Lst[t * 49 + c] + dec2_b[c];
        float m = lg[1];
#pragma unroll
        for (int c = 2; c < 36; ++c) m = fmaxf(m, lg[c]);
        float d[35];
        float s = 0.f;
#pragma unroll
        for (int c = 1; c < 36; ++c) { float e = expf(lg[c] - m); d[c - 1] = e; s += e; }
        float inv = 1.0f / s;
        float* dout = out + (size_t)row * 35;
#pragma unroll
        for (int j = 0; j < 35; ++j) dout[j] = d[j] * inv;
        float best = -1.f; int bi = 1;
#pragma unroll
        for (int c = 1; c < 35; ++c) {
            float v = d[c] * inv;
            if (v > best) { best = v; bi = c; }
        }
        out[(size_t)NROWS * 35 + row] = best;
        out[(size_t)NROWS * 36 + row] = (float)(bi + 1);
    }
}

// ---------------- per-image human argmax over dist[:,0] (proven R2 code) ----------------
__global__ __launch_bounds__(64) void k4_human(float* __restrict__ out)
{
    int b = blockIdx.x;
    int t = threadIdx.x;
    int row = b * PER + t;
    float v = out[(size_t)row * 35 + 0];
    int idx = t;
#pragma unroll
    for (int off = 32; off > 0; off >>= 1) {
        float ov = __shfl_down(v, off);
        int   oi = __shfl_down(idx, off);
        if (ov > v || (ov == v && oi < idx)) { v = ov; idx = oi; }
    }
    if (t == 0) {
        int human = b * PER + idx;
        out[(size_t)NROWS * 37 + b] = (float)human;
        out[(size_t)NROWS * 35 + human] = v;
        out[(size_t)NROWS * 36 + human] = 1.0f;
    }
}

extern "C" void kernel_launch(void* const* d_in, const int* in_sizes, int n_in,
                              void* d_out, int out_size, void* d_ws, size_t ws_size,
                              hipStream_t stream)
{
    (void)in_sizes; (void)n_in; (void)out_size; (void)ws_size;
    const float* distribution = (const float*)d_in[0];
    const float* features     = (const float*)d_in[1];
    const float* boxes        = (const float*)d_in[2];
    const float* obj_embed_W  = (const float*)d_in[3];
    const float* bn4_g        = (const float*)d_in[4];
    const float* bn4_b        = (const float*)d_in[5];
    const float* bn4_m        = (const float*)d_in[6];
    const float* bn4_v        = (const float*)d_in[7];
    const float* pos_W        = (const float*)d_in[8];
    const float* pos_b        = (const float*)d_in[9];
    const float* dec1_W       = (const float*)d_in[10];
    const float* dec1_b       = (const float*)d_in[11];
    const float* bn1k_g       = (const float*)d_in[12];
    const float* bn1k_b       = (const float*)d_in[13];
    const float* bn1k_m       = (const float*)d_in[14];
    const float* bn1k_v       = (const float*)d_in[15];
    const float* dec2_W       = (const float*)d_in[16];
    const float* dec2_b       = (const float*)d_in[17];

    float* out = (float*)d_out;

    // ws layout (1.78 MB total)
    unsigned short* W1fT_h = (unsigned short*)d_ws;                 // 1024*384
    unsigned short* W1fT_l = W1fT_h + (size_t)HID * KP;
    unsigned short* W2T_h  = W1fT_l + (size_t)HID * KP;             // 48*1024
    unsigned short* W2T_l  = W2T_h + (size_t)48 * W2KP;
    float*          bsv    = (float*)(W2T_l + (size_t)48 * W2KP);   // 1024

    const int LDS_BYTES = (2 * 64 * XSTR + 2 * 64 * GCSTR) * 2;     // 118784
    hipFuncSetAttribute((const void*)k_main,
                        hipFuncAttributeMaxDynamicSharedMemorySize, LDS_BYTES);

    int prep_elems = HID * KP + 48 * W2KP;
    k_prep<<<(prep_elems + 255) / 256, 256, 0, stream>>>(
        obj_embed_W, dec1_W, dec1_b, bn1k_g, bn1k_b, bn1k_m, bn1k_v, dec2_W,
        W1fT_h, W1fT_l, W2T_h, W2T_l, bsv);

    k_main<<<BIMG, 256, LDS_BYTES, stream>>>(
        distribution, features, boxes, bn4_g, bn4_b, bn4_m, bn4_v, pos_W, pos_b,
        W1fT_h, W1fT_l, W2T_h, W2T_l, bsv, dec2_b, out);

    k4_human<<<BIMG, 64, 0, stream>>>(out);
}

// Round 4
// 335.089 us; speedup vs baseline: 3.4564x; 1.8772x over previous
//
#include <hip/hip_runtime.h>
#include <math.h>

#define NROWS 65536
#define PER 64
#define BIMG 1024
#define NCLS 36
#define OBJ_DIM 192
#define EMB 200
#define POSD 128
#define HID 1024
#define EPSV 1e-5f

#define KP 384            // padded K for GEMM1 (355 real -> 384)
#define XSTR 392          // Xs LDS row stride in fp16 units
#define GCSTR 72          // Gc row stride in fp16 units (64 + 8)
#define W2KP 1024         // W2T k stride

typedef __attribute__((ext_vector_type(8))) _Float16 f16x8;
typedef __attribute__((ext_vector_type(4))) _Float16 f16x4;
typedef __attribute__((ext_vector_type(4))) float f32x4;

// ---------------- prep: fused+scaled W1f^T (fp16), W2^T (fp16), bias vector ----------------
// W1fT[h][k]: k<192 -> dec1_W[k][h]; 192..226 -> (obj_embed_W @ dec1_W[192:392])[k-192][h];
// 227..354 -> dec1_W[k+165][h]; >=355 -> 0.  All scaled by bn1k scale sc[h].
__global__ __launch_bounds__(256) void k_prep(
    const float* __restrict__ obj_embed_W, const float* __restrict__ dec1_W,
    const float* __restrict__ dec1_b,
    const float* __restrict__ bn1k_g, const float* __restrict__ bn1k_b,
    const float* __restrict__ bn1k_m, const float* __restrict__ bn1k_v,
    const float* __restrict__ dec2_W,
    _Float16* __restrict__ W1fT, _Float16* __restrict__ W2T,
    float* __restrict__ bs)
{
    int idx = blockIdx.x * 256 + threadIdx.x;
    if (idx < HID * KP) {
        int h = idx / KP, k = idx % KP;
        float sc = rsqrtf(bn1k_v[h] + EPSV) * bn1k_g[h];
        float v;
        if (k < 192) v = dec1_W[(size_t)k * HID + h];
        else if (k < 227) {
            int e = k - 192; float acc = 0.f;
            for (int j = 0; j < EMB; ++j)
                acc = fmaf(obj_embed_W[e * EMB + j], dec1_W[(size_t)(192 + j) * HID + h], acc);
            v = acc;
        } else if (k < 355) v = dec1_W[(size_t)(k - 227 + 392) * HID + h];
        else v = 0.f;
        W1fT[(size_t)h * KP + k] = (_Float16)(v * sc);
        if (k == 0) bs[h] = (dec1_b[h] - bn1k_m[h]) * sc + bn1k_b[h];
    } else {
        int j = idx - HID * KP;           // 48 * 1024 region
        if (j < 48 * W2KP) {
            int c = j / W2KP, h2 = j % W2KP;
            float v = (c < NCLS) ? dec2_W[(size_t)h2 * NCLS + c] : 0.f;
            W2T[j] = (_Float16)v;
        }
    }
}

// ---------------- main fused kernel: 64 rows/block, fp16 MFMA ----------------
__global__ __launch_bounds__(256, 2) void k_main(
    const float* __restrict__ distribution, const float* __restrict__ features,
    const float* __restrict__ boxes,
    const float* __restrict__ bn4_g, const float* __restrict__ bn4_b,
    const float* __restrict__ bn4_m, const float* __restrict__ bn4_v,
    const float* __restrict__ pos_W, const float* __restrict__ pos_b,
    const _Float16* __restrict__ W1fT, const _Float16* __restrict__ W2T,
    const float* __restrict__ bs, const float* __restrict__ dec2_b,
    float* __restrict__ out)
{
    __shared__ __align__(16) char smem[62720];
    _Float16* Xs = (_Float16*)smem;                // 64*392 fp16 = 50176 B
    _Float16* Gc = (_Float16*)(smem + 50176);      // 64*72 fp16 = 9216 B
    float* Lst   = (float*)(smem + 50176);         // aliases Gc (64*49*4 = 12544 B)

    int t = threadIdx.x;
    int row0 = blockIdx.x * PER;

    // ---- stage X = [features | distribution | pos] as fp16, K padded to 384 ----
    {
        int r = t >> 2;            // 0..63 local row
        int kq = t & 3;            // k quarter (96 each)
        int grow = row0 + r;
        const float* bx = boxes + (size_t)grow * 5;
        float x1 = bx[1], y1 = bx[2], x2 = bx[3], y2 = bx[4];
        float w = x2 - x1 + 1.f, hh = y2 - y1 + 1.f;
        float cs[4] = {x1 + 0.5f * w, y1 + 0.5f * hh, w, hh};
        float hv[4];
#pragma unroll
        for (int i = 0; i < 4; i++)
            hv[i] = (cs[i] - bn4_m[i]) * rsqrtf(bn4_v[i] + EPSV) * bn4_g[i] + bn4_b[i];
        for (int jb = 0; jb < 12; ++jb) {
            int kb = kq * 96 + jb * 8;
            f16x8 v8;
#pragma unroll
            for (int e = 0; e < 8; ++e) {
                int k = kb + e;
                float v;
                if (k < 192) v = features[(size_t)grow * OBJ_DIM + k];
                else if (k < 227) v = distribution[(size_t)grow * (NCLS - 1) + (k - 192)];
                else if (k < 355) {
                    int j = k - 227;
                    float p = pos_b[j];
                    p = fmaf(hv[0], pos_W[j], p);
                    p = fmaf(hv[1], pos_W[POSD + j], p);
                    p = fmaf(hv[2], pos_W[2 * POSD + j], p);
                    p = fmaf(hv[3], pos_W[3 * POSD + j], p);
                    v = fmaxf(p, 0.f);
                } else v = 0.f;
                v8[e] = (_Float16)v;
            }
            *(f16x8*)&Xs[r * XSTR + kb] = v8;
        }
    }
    __syncthreads();

    int wv = t >> 6, lane = t & 63, lr = lane & 15, lq = lane >> 4;

    f32x4 Lg[3];                       // logit frags: rows 16wv..+15 x classes 48
#pragma unroll
    for (int n = 0; n < 3; n++) Lg[n] = (f32x4){0.f, 0.f, 0.f, 0.f};

    for (int c0 = 0; c0 < 4; ++c0) {   // hidden chunks of 256
        int H0 = c0 * 256;
        f32x4 C[4][4];
#pragma unroll
        for (int j = 0; j < 4; j++)
#pragma unroll
            for (int n = 0; n < 4; n++) C[j][n] = (f32x4){0.f, 0.f, 0.f, 0.f};

        // ---- GEMM1 K-loop: no barriers (Xs read-only) ----
        for (int ks = 0; ks < 12; ++ks) {
            int k0 = ks * 32 + lq * 8;
            f16x8 ah[4], bh[4];
#pragma unroll
            for (int j = 0; j < 4; j++)
                ah[j] = *(const f16x8*)(W1fT + (size_t)(H0 + 16 * (wv + 4 * j) + lr) * KP + k0);
#pragma unroll
            for (int n = 0; n < 4; n++)
                bh[n] = *(const f16x8*)&Xs[(16 * n + lr) * XSTR + k0];
#pragma unroll
            for (int j = 0; j < 4; j++)
#pragma unroll
                for (int n = 0; n < 4; n++)
                    C[j][n] = __builtin_amdgcn_mfma_f32_16x16x32_f16(ah[j], bh[n], C[j][n], 0, 0, 0);
        }

        // ---- transform + GEMM2, 4 sub-rounds of 64 hidden ----
        for (int j = 0; j < 4; ++j) {
            __syncthreads();           // Gc free (previous GEMM2 done)
            int hb = H0 + 16 * (wv + 4 * j) + 4 * lq;
            f32x4 bsv = *(const f32x4*)(bs + hb);
#pragma unroll
            for (int n = 0; n < 4; n++) {
                f16x4 g4;
#pragma unroll
                for (int e = 0; e < 4; ++e)
                    g4[e] = (_Float16)fmaxf(C[j][n][e] + bsv[e], 0.f);
                *(f16x4*)&Gc[(16 * n + lr) * GCSTR + 16 * wv + 4 * lq] = g4;
            }
            __syncthreads();           // Gc filled
#pragma unroll
            for (int ks2 = 0; ks2 < 2; ++ks2) {
                int kl = ks2 * 32 + lq * 8;
                f16x8 a2 = *(const f16x8*)&Gc[(16 * wv + lr) * GCSTR + kl];
                int hg = H0 + 64 * j + kl;
#pragma unroll
                for (int n = 0; n < 3; n++) {
                    f16x8 b2 = *(const f16x8*)(W2T + (size_t)(16 * n + lr) * W2KP + hg);
                    Lg[n] = __builtin_amdgcn_mfma_f32_16x16x32_f16(a2, b2, Lg[n], 0, 0, 0);
                }
            }
        }
    }

    __syncthreads();                   // Gc region now reused as logit stash
#pragma unroll
    for (int n = 0; n < 3; n++)
#pragma unroll
        for (int e = 0; e < 4; ++e)
            Lst[(16 * wv + 4 * lq + e) * 49 + 16 * n + lr] = Lg[n][e];
    __syncthreads();

    // ---- softmax head + fused per-image human argmax (t<64 == wave 0) ----
    if (t < 64) {
        int row = row0 + t;
        float lg[36];
#pragma unroll
        for (int c = 1; c < 36; ++c) lg[c] = Lst[t * 49 + c] + dec2_b[c];
        float m = lg[1];
#pragma unroll
        for (int c = 2; c < 36; ++c) m = fmaxf(m, lg[c]);
        float d[35];
        float s = 0.f;
#pragma unroll
        for (int c = 1; c < 36; ++c) { float e = expf(lg[c] - m); d[c - 1] = e; s += e; }
        float inv = 1.0f / s;
        float* dout = out + (size_t)row * 35;
#pragma unroll
        for (int j = 0; j < 35; ++j) dout[j] = d[j] * inv;

        // per-row argmax over dist cols 1..34 (first-occurrence), label = distcol+1
        float best = -1.f; int bi = 1;
#pragma unroll
        for (int c = 1; c < 35; ++c) {
            float v = d[c] * inv;
            if (v > best) { best = v; bi = c; }
        }

        // block == image: argmax over dist[:,0] across the 64 lanes
        float v0 = d[0] * inv;
        float mv = v0; int mi = t;
#pragma unroll
        for (int off = 32; off > 0; off >>= 1) {
            float ov = __shfl_down(mv, off);
            int   oi = __shfl_down(mi, off);
            if (ov > mv || (ov == mv && oi < mi)) { mv = ov; mi = oi; }
        }
        int human = __shfl(mi, 0);     // local row of the human
        bool isH = (t == human);
        out[(size_t)NROWS * 35 + row] = isH ? v0 : best;
        out[(size_t)NROWS * 36 + row] = isH ? 1.0f : (float)(bi + 1);
        if (t == 0) out[(size_t)NROWS * 37 + blockIdx.x] = (float)(row0 + human);
    }
}

extern "C" void kernel_launch(void* const* d_in, const int* in_sizes, int n_in,
                              void* d_out, int out_size, void* d_ws, size_t ws_size,
                              hipStream_t stream)
{
    (void)in_sizes; (void)n_in; (void)out_size; (void)ws_size;
    const float* distribution = (const float*)d_in[0];
    const float* features     = (const float*)d_in[1];
    const float* boxes        = (const float*)d_in[2];
    const float* obj_embed_W  = (const float*)d_in[3];
    const float* bn4_g        = (const float*)d_in[4];
    const float* bn4_b        = (const float*)d_in[5];
    const float* bn4_m        = (const float*)d_in[6];
    const float* bn4_v        = (const float*)d_in[7];
    const float* pos_W        = (const float*)d_in[8];
    const float* pos_b        = (const float*)d_in[9];
    const float* dec1_W       = (const float*)d_in[10];
    const float* dec1_b       = (const float*)d_in[11];
    const float* bn1k_g       = (const float*)d_in[12];
    const float* bn1k_b       = (const float*)d_in[13];
    const float* bn1k_m       = (const float*)d_in[14];
    const float* bn1k_v       = (const float*)d_in[15];
    const float* dec2_W       = (const float*)d_in[16];
    const float* dec2_b       = (const float*)d_in[17];

    float* out = (float*)d_out;

    // ws layout (~0.9 MB)
    _Float16* W1fT = (_Float16*)d_ws;                      // 1024*384
    _Float16* W2T  = W1fT + (size_t)HID * KP;              // 48*1024
    float*    bsv  = (float*)(W2T + (size_t)48 * W2KP);    // 1024

    int prep_elems = HID * KP + 48 * W2KP;
    k_prep<<<(prep_elems + 255) / 256, 256, 0, stream>>>(
        obj_embed_W, dec1_W, dec1_b, bn1k_g, bn1k_b, bn1k_m, bn1k_v, dec2_W,
        W1fT, W2T, bsv);

    k_main<<<BIMG, 256, 0, stream>>>(
        distribution, features, boxes, bn4_g, bn4_b, bn4_m, bn4_v, pos_W, pos_b,
        W1fT, W2T, bsv, dec2_b, out);
}